// Round 1
// baseline (243.193 us; speedup 1.0000x reference)
//
#include <hip/hip_runtime.h>
#include <math.h>

// Problem constants (fixed by the reference)
#define NN 2048      // N = B*NA nodes
#define DD 128       // feature dim
#define HH 6         // heads
#define HD 768       // H*D
#define NA 32        // agents per scene
#define NB 64        // scenes

// ---------------------------------------------------------------------------
// Kernel 1: Q/K/V projection + LayerNorm(768) (+relu for V), 8 nodes / block
// ---------------------------------------------------------------------------
__global__ __launch_bounds__(256) void qkv_ln_kernel(
    const float* __restrict__ agents,
    const float* __restrict__ Wq, const float* __restrict__ gq, const float* __restrict__ bq,
    const float* __restrict__ Wk, const float* __restrict__ gk, const float* __restrict__ bk,
    const float* __restrict__ Wv, const float* __restrict__ gv, const float* __restrict__ bv,
    float* __restrict__ Q, float* __restrict__ K, float* __restrict__ V)
{
    __shared__ float A_s[8][128];     // 8 agent rows
    __shared__ float red[4][8][2];    // per-wave partial {sum, sumsq} per node
    const int tid = threadIdx.x;
    const int n0 = blockIdx.x * 8;

    // stage 8 agent rows (1024 floats = 256 float4)
    {
        const float4* src = (const float4*)(agents + (size_t)n0 * 128);
        ((float4*)&A_s[0][0])[tid] = src[tid];
    }
    __syncthreads();

    const float* Wm[3] = {Wq, Wk, Wv};
    const float* gm[3] = {gq, gk, gv};
    const float* bm[3] = {bq, bk, bv};
    float*       Om[3] = {Q, K, V};

    const int lane = tid & 63;
    const int wid  = tid >> 6;

    for (int m = 0; m < 3; ++m) {
        float acc[3][8];
        #pragma unroll
        for (int j = 0; j < 3; ++j)
            #pragma unroll
            for (int n = 0; n < 8; ++n) acc[j][n] = 0.f;

        #pragma unroll
        for (int j = 0; j < 3; ++j) {
            const int c = tid + j * 256;
            const float4* wrow = (const float4*)(Wm[m] + (size_t)c * 128);
            #pragma unroll 4
            for (int k4 = 0; k4 < 32; ++k4) {
                const float4 w = wrow[k4];
                #pragma unroll
                for (int n = 0; n < 8; ++n) {
                    const float4 a = *(const float4*)&A_s[n][k4 * 4];
                    acc[j][n] += w.x * a.x + w.y * a.y + w.z * a.z + w.w * a.w;
                }
            }
        }

        // LayerNorm stats over 768 per node
        float ps[8], pq[8];
        #pragma unroll
        for (int n = 0; n < 8; ++n) {
            ps[n] = acc[0][n] + acc[1][n] + acc[2][n];
            pq[n] = acc[0][n] * acc[0][n] + acc[1][n] * acc[1][n] + acc[2][n] * acc[2][n];
        }
        #pragma unroll
        for (int n = 0; n < 8; ++n) {
            #pragma unroll
            for (int mask = 32; mask >= 1; mask >>= 1) {
                ps[n] += __shfl_xor(ps[n], mask);
                pq[n] += __shfl_xor(pq[n], mask);
            }
        }
        if (lane == 0) {
            #pragma unroll
            for (int n = 0; n < 8; ++n) { red[wid][n][0] = ps[n]; red[wid][n][1] = pq[n]; }
        }
        __syncthreads();

        float mean[8], rstd[8];
        #pragma unroll
        for (int n = 0; n < 8; ++n) {
            const float s  = red[0][n][0] + red[1][n][0] + red[2][n][0] + red[3][n][0];
            const float q2 = red[0][n][1] + red[1][n][1] + red[2][n][1] + red[3][n][1];
            const float mu  = s * (1.f / 768.f);
            const float var = q2 * (1.f / 768.f) - mu * mu;
            mean[n] = mu;
            rstd[n] = rsqrtf(var + 1e-5f);
        }

        const bool isV = (m == 2);
        #pragma unroll
        for (int j = 0; j < 3; ++j) {
            const int c = tid + j * 256;
            const float g = gm[m][c], b = bm[m][c];
            #pragma unroll
            for (int n = 0; n < 8; ++n) {
                float v = (acc[j][n] - mean[n]) * rstd[n] * g + b;
                if (isV) v = fmaxf(v, 0.f);
                Om[m][(size_t)(n0 + n) * HD + c] = v;
            }
        }
        __syncthreads();  // protect red[] before next matrix
    }
}

// ---------------------------------------------------------------------------
// Kernel 2: per-(scene, head) attention: S = QK^T*scale, softmax rows, O = PV
// ---------------------------------------------------------------------------
__global__ __launch_bounds__(256) void attn_kernel(
    const float* __restrict__ Q, const float* __restrict__ K, const float* __restrict__ V,
    float* __restrict__ O)
{
    __shared__ float Qs[32][136];   // pitch 136: <=2-way conflicts on reads
    __shared__ float Ks[32][136];
    __shared__ float Vs[32][136];
    __shared__ float Ss[32][33];
    const int tid = threadIdx.x;
    const int scene = blockIdx.x, h = blockIdx.y;
    const size_t base = (size_t)scene * NA * HD + (size_t)h * 128;

    // stage Q/K/V 32x128 tiles
    {
        const int row = tid >> 3;        // 0..31
        const int f4  = tid & 7;
        #pragma unroll
        for (int rep = 0; rep < 4; ++rep) {
            const int col = (f4 + rep * 8) * 4;
            const size_t g = base + (size_t)row * HD + col;
            *(float4*)&Qs[row][col] = *(const float4*)(Q + g);
            *(float4*)&Ks[row][col] = *(const float4*)(K + g);
            *(float4*)&Vs[row][col] = *(const float4*)(V + g);
        }
    }
    __syncthreads();

    // S = scale * Q K^T  (2x2 register blocking)
    {
        const int ti = tid >> 4, tj = tid & 15;
        float a00 = 0.f, a01 = 0.f, a10 = 0.f, a11 = 0.f;
        #pragma unroll 4
        for (int k4 = 0; k4 < 32; ++k4) {
            const float4 q0 = *(const float4*)&Qs[2 * ti][k4 * 4];
            const float4 q1 = *(const float4*)&Qs[2 * ti + 1][k4 * 4];
            const float4 k0 = *(const float4*)&Ks[2 * tj][k4 * 4];
            const float4 k1 = *(const float4*)&Ks[2 * tj + 1][k4 * 4];
            a00 += q0.x * k0.x + q0.y * k0.y + q0.z * k0.z + q0.w * k0.w;
            a01 += q0.x * k1.x + q0.y * k1.y + q0.z * k1.z + q0.w * k1.w;
            a10 += q1.x * k0.x + q1.y * k0.y + q1.z * k0.z + q1.w * k0.w;
            a11 += q1.x * k1.x + q1.y * k1.y + q1.z * k1.z + q1.w * k1.w;
        }
        const float scale = 0.08838834764831845f;  // 1/sqrt(128)
        Ss[2 * ti][2 * tj]         = a00 * scale;
        Ss[2 * ti][2 * tj + 1]     = a01 * scale;
        Ss[2 * ti + 1][2 * tj]     = a10 * scale;
        Ss[2 * ti + 1][2 * tj + 1] = a11 * scale;
    }
    __syncthreads();

    // softmax over each row of 32 (global-max in the reference cancels exactly)
    {
        const int g = tid >> 5, l = tid & 31;   // 8 groups of 32 lanes
        #pragma unroll
        for (int ib = 0; ib < 4; ++ib) {
            const int i = g + ib * 8;
            const float s = Ss[i][l];
            float mx = s;
            #pragma unroll
            for (int mask = 16; mask >= 1; mask >>= 1)
                mx = fmaxf(mx, __shfl_xor(mx, mask));
            const float p = __expf(s - mx);
            float sum = p;
            #pragma unroll
            for (int mask = 16; mask >= 1; mask >>= 1)
                sum += __shfl_xor(sum, mask);
            Ss[i][l] = p / sum;
        }
    }
    __syncthreads();

    // O = P V   (thread: row i = tid/8, cols dg*4 + 32r)
    {
        const int i = tid >> 3, dg = tid & 7;
        float o[4][4] = {};
        for (int j = 0; j < 32; ++j) {
            const float p = Ss[i][j];
            #pragma unroll
            for (int r = 0; r < 4; ++r) {
                const float4 v4 = *(const float4*)&Vs[j][dg * 4 + 32 * r];
                o[r][0] += p * v4.x; o[r][1] += p * v4.y;
                o[r][2] += p * v4.z; o[r][3] += p * v4.w;
            }
        }
        #pragma unroll
        for (int r = 0; r < 4; ++r) {
            *(float4*)(O + base + (size_t)i * HD + dg * 4 + 32 * r) =
                make_float4(o[r][0], o[r][1], o[r][2], o[r][3]);
        }
    }
}

// ---------------------------------------------------------------------------
// Kernel 3: fused epilogue, 8 nodes / block:
//   t = relu(LN(O @ Wo1^T)); u = t @ Wo2^T; n1 = A @ W1^T;
//   z = relu(LN(n1 + u));    out = relu(z @ W2^T + A)
// ---------------------------------------------------------------------------
__global__ __launch_bounds__(256) void epilogue_kernel(
    const float* __restrict__ O, const float* __restrict__ agents,
    const float* __restrict__ Wo1, const float* __restrict__ go, const float* __restrict__ bo,
    const float* __restrict__ Wo2, const float* __restrict__ W1,
    const float* __restrict__ gn, const float* __restrict__ bn,
    const float* __restrict__ W2, float* __restrict__ out)
{
    __shared__ float Os[8][768];
    __shared__ float As[8][128];
    __shared__ float ts[8][128];
    __shared__ float zs[8][128];
    __shared__ float redS[4][4], redQ[4][4];
    const int tid = threadIdx.x;
    const int n0 = blockIdx.x * 8;

    {
        const float4* src = (const float4*)(O + (size_t)n0 * HD);
        float4* dst = (float4*)&Os[0][0];
        #pragma unroll
        for (int r = 0; r < 6; ++r) dst[tid + r * 256] = src[tid + r * 256];
        const float4* asrc = (const float4*)(agents + (size_t)n0 * 128);
        ((float4*)&As[0][0])[tid] = asrc[tid];
    }
    __syncthreads();

    const int c  = tid & 127;       // output column
    const int rg = tid >> 7;        // 0..1 -> rows rg*4 .. rg*4+3
    const int lane = tid & 63;
    const int wid  = tid >> 6;

    // ---- t = O @ Wo1^T (K = 768) ----
    float acc[4] = {0.f, 0.f, 0.f, 0.f};
    {
        const float4* wrow = (const float4*)(Wo1 + (size_t)c * HD);
        #pragma unroll 4
        for (int k4 = 0; k4 < 192; ++k4) {
            const float4 w = wrow[k4];
            #pragma unroll
            for (int j = 0; j < 4; ++j) {
                const float4 a = *(const float4*)&Os[rg * 4 + j][k4 * 4];
                acc[j] += w.x * a.x + w.y * a.y + w.z * a.z + w.w * a.w;
            }
        }
    }
    // LN(128) stats per row: wave-reduce then combine the group's 2 waves
    {
        float ps[4], pq[4];
        #pragma unroll
        for (int j = 0; j < 4; ++j) { ps[j] = acc[j]; pq[j] = acc[j] * acc[j]; }
        #pragma unroll
        for (int j = 0; j < 4; ++j) {
            #pragma unroll
            for (int mask = 32; mask >= 1; mask >>= 1) {
                ps[j] += __shfl_xor(ps[j], mask);
                pq[j] += __shfl_xor(pq[j], mask);
            }
        }
        if (lane == 0) {
            #pragma unroll
            for (int j = 0; j < 4; ++j) { redS[wid][j] = ps[j]; redQ[wid][j] = pq[j]; }
        }
        __syncthreads();
        const float g_ = go[c], b_ = bo[c];
        #pragma unroll
        for (int j = 0; j < 4; ++j) {
            const float s  = redS[rg * 2][j] + redS[rg * 2 + 1][j];
            const float q2 = redQ[rg * 2][j] + redQ[rg * 2 + 1][j];
            const float mu  = s * (1.f / 128.f);
            const float var = q2 * (1.f / 128.f) - mu * mu;
            const float v = (acc[j] - mu) * rsqrtf(var + 1e-5f) * g_ + b_;
            ts[rg * 4 + j][c] = fmaxf(v, 0.f);
        }
    }
    __syncthreads();

    // ---- u = t @ Wo2^T ; n1 = A @ W1^T ; val = u + n1 (K = 128) ----
    float acc2[4] = {0.f, 0.f, 0.f, 0.f};
    {
        const float4* w2row = (const float4*)(Wo2 + (size_t)c * 128);
        const float4* w1row = (const float4*)(W1 + (size_t)c * 128);
        #pragma unroll 4
        for (int k4 = 0; k4 < 32; ++k4) {
            const float4 w2 = w2row[k4];
            const float4 w1 = w1row[k4];
            #pragma unroll
            for (int j = 0; j < 4; ++j) {
                const float4 t4 = *(const float4*)&ts[rg * 4 + j][k4 * 4];
                const float4 a4 = *(const float4*)&As[rg * 4 + j][k4 * 4];
                acc2[j] += w2.x * t4.x + w2.y * t4.y + w2.z * t4.z + w2.w * t4.w
                         + w1.x * a4.x + w1.y * a4.y + w1.z * a4.z + w1.w * a4.w;
            }
        }
    }
    // LN(128) + relu -> zs
    {
        float ps[4], pq[4];
        #pragma unroll
        for (int j = 0; j < 4; ++j) { ps[j] = acc2[j]; pq[j] = acc2[j] * acc2[j]; }
        #pragma unroll
        for (int j = 0; j < 4; ++j) {
            #pragma unroll
            for (int mask = 32; mask >= 1; mask >>= 1) {
                ps[j] += __shfl_xor(ps[j], mask);
                pq[j] += __shfl_xor(pq[j], mask);
            }
        }
        __syncthreads();   // make sure stage-1 reads of redS/redQ are done
        if (lane == 0) {
            #pragma unroll
            for (int j = 0; j < 4; ++j) { redS[wid][j] = ps[j]; redQ[wid][j] = pq[j]; }
        }
        __syncthreads();
        const float g_ = gn[c], b_ = bn[c];
        #pragma unroll
        for (int j = 0; j < 4; ++j) {
            const float s  = redS[rg * 2][j] + redS[rg * 2 + 1][j];
            const float q2 = redQ[rg * 2][j] + redQ[rg * 2 + 1][j];
            const float mu  = s * (1.f / 128.f);
            const float var = q2 * (1.f / 128.f) - mu * mu;
            const float v = (acc2[j] - mu) * rsqrtf(var + 1e-5f) * g_ + b_;
            zs[rg * 4 + j][c] = fmaxf(v, 0.f);
        }
    }
    __syncthreads();

    // ---- out = relu(z @ W2^T + A) ----
    float acc3[4] = {0.f, 0.f, 0.f, 0.f};
    {
        const float4* wrow = (const float4*)(W2 + (size_t)c * 128);
        #pragma unroll 4
        for (int k4 = 0; k4 < 32; ++k4) {
            const float4 w = wrow[k4];
            #pragma unroll
            for (int j = 0; j < 4; ++j) {
                const float4 z4 = *(const float4*)&zs[rg * 4 + j][k4 * 4];
                acc3[j] += w.x * z4.x + w.y * z4.y + w.z * z4.z + w.w * z4.w;
            }
        }
    }
    #pragma unroll
    for (int j = 0; j < 4; ++j) {
        const int r = rg * 4 + j;
        out[(size_t)(n0 + r) * 128 + c] = fmaxf(acc3[j] + As[r][c], 0.f);
    }
}

// ---------------------------------------------------------------------------
extern "C" void kernel_launch(void* const* d_in, const int* in_sizes, int n_in,
                              void* d_out, int out_size, void* d_ws, size_t ws_size,
                              hipStream_t stream) {
    (void)in_sizes; (void)n_in; (void)out_size; (void)ws_size;
    const float* agents = (const float*)d_in[0];
    // d_in[1] = hi, d_in[2] = wi: deterministic fully-connected edge list; not needed.
    const float* Wq  = (const float*)d_in[3];
    const float* gq  = (const float*)d_in[4];
    const float* bq  = (const float*)d_in[5];
    const float* Wk  = (const float*)d_in[6];
    const float* gk  = (const float*)d_in[7];
    const float* bk  = (const float*)d_in[8];
    const float* Wv  = (const float*)d_in[9];
    const float* gv  = (const float*)d_in[10];
    const float* bv  = (const float*)d_in[11];
    const float* Wo1 = (const float*)d_in[12];
    const float* go  = (const float*)d_in[13];
    const float* bo  = (const float*)d_in[14];
    const float* Wo2 = (const float*)d_in[15];
    const float* W1  = (const float*)d_in[16];
    const float* gn  = (const float*)d_in[17];
    const float* bn  = (const float*)d_in[18];
    const float* W2  = (const float*)d_in[19];
    float* out = (float*)d_out;

    float* ws = (float*)d_ws;
    float* Q = ws;
    float* K = ws + (size_t)NN * HD;
    float* V = ws + (size_t)NN * HD * 2;
    float* O = ws + (size_t)NN * HD * 3;

    qkv_ln_kernel<<<NN / 8, 256, 0, stream>>>(agents, Wq, gq, bq, Wk, gk, bk,
                                              Wv, gv, bv, Q, K, V);
    attn_kernel<<<dim3(NB, HH), 256, 0, stream>>>(Q, K, V, O);
    epilogue_kernel<<<NN / 8, 256, 0, stream>>>(O, agents, Wo1, go, bo, Wo2, W1,
                                                gn, bn, W2, out);
}

// Round 3
// 236.367 us; speedup vs baseline: 1.0289x; 1.0289x over previous
//
#include <hip/hip_runtime.h>
#include <math.h>

#define NN 2048      // nodes
#define DD 128       // feature dim
#define HH 6         // heads
#define HD 768       // H*D
#define NA 32        // agents/scene
#define NB 64        // scenes

__device__ __forceinline__ float dot4(float4 a, float4 b) {
    return a.x * b.x + a.y * b.y + a.z * b.z + a.w * b.w;
}

// ---------------------------------------------------------------------------
// K1: raw projections R[m] = agents @ Wm^T  (no LN yet), per-chunk LN partials.
// Block: 128 thr = 16 colgrps x 8 nodes; 8 cols/thread; grid (256, 6, 3).
// ---------------------------------------------------------------------------
__global__ __launch_bounds__(128) void proj_gemm_kernel(
    const float* __restrict__ agents,
    const float* __restrict__ Wq, const float* __restrict__ Wk, const float* __restrict__ Wv,
    float* __restrict__ R,    // [3][2048][768] raw
    float* __restrict__ ps)   // [3][2048][6][2] partial {sum, sumsq}
{
    __shared__ float A_s[8][132];       // pitch 132: banks offset 4/row -> conflict-free
    __shared__ float red[2][8][2];
    const int tid = threadIdx.x;
    const int cg = tid >> 3, n = tid & 7;
    const int ng = blockIdx.x, chunk = blockIdx.y, m = blockIdx.z;
    const int n0 = ng * 8;
    const float* W = (m == 0) ? Wq : (m == 1) ? Wk : Wv;

    // stage 8 agent rows (256 float4, 2 per thread)
    {
        const float4* src = (const float4*)(agents + (size_t)n0 * 128);
        #pragma unroll
        for (int r = 0; r < 2; ++r) {
            const int idx = tid + r * 128;
            const int row = idx >> 5, c4 = idx & 31;
            *(float4*)&A_s[row][c4 * 4] = src[idx];
        }
    }
    __syncthreads();

    const int colbase = chunk * 128 + cg * 8;
    const float* wbase = W + (size_t)colbase * 128;
    float acc[8] = {0.f, 0.f, 0.f, 0.f, 0.f, 0.f, 0.f, 0.f};

    for (int k4 = 0; k4 < 32; k4 += 2) {
        const float4 a0 = *(const float4*)&A_s[n][k4 * 4];
        const float4 a1 = *(const float4*)&A_s[n][k4 * 4 + 4];
        #pragma unroll
        for (int jj = 0; jj < 8; ++jj) {
            const float4 w0 = *(const float4*)(wbase + (size_t)jj * 128 + k4 * 4);
            const float4 w1 = *(const float4*)(wbase + (size_t)jj * 128 + k4 * 4 + 4);
            acc[jj] += dot4(a0, w0) + dot4(a1, w1);
        }
    }

    // per-chunk LN partials: reduce over 16 colgrps
    float s = 0.f, q = 0.f;
    #pragma unroll
    for (int jj = 0; jj < 8; ++jj) { s += acc[jj]; q += acc[jj] * acc[jj]; }
    #pragma unroll
    for (int mask = 8; mask <= 32; mask <<= 1) {
        s += __shfl_xor(s, mask);
        q += __shfl_xor(q, mask);
    }
    if ((tid & 63) < 8) { red[tid >> 6][tid & 7][0] = s; red[tid >> 6][tid & 7][1] = q; }
    __syncthreads();
    if (tid < 8) {
        const size_t o = ((size_t)m * NN + n0 + tid) * 12 + chunk * 2;
        ps[o]     = red[0][tid][0] + red[1][tid][0];
        ps[o + 1] = red[0][tid][1] + red[1][tid][1];
    }

    float* rout = R + ((size_t)m * NN + n0 + n) * HD + colbase;
    *(float4*)rout       = make_float4(acc[0], acc[1], acc[2], acc[3]);
    *(float4*)(rout + 4) = make_float4(acc[4], acc[5], acc[6], acc[7]);
}

// ---------------------------------------------------------------------------
// K2: per-(scene, head) attention; applies LN (q,k) and LN+relu (v) during
// LDS staging from raw R + partial stats.
// ---------------------------------------------------------------------------
__global__ __launch_bounds__(256) void attn_kernel(
    const float* __restrict__ R, const float* __restrict__ ps,
    const float* __restrict__ gq, const float* __restrict__ bq,
    const float* __restrict__ gk, const float* __restrict__ bk,
    const float* __restrict__ gv, const float* __restrict__ bv,
    float* __restrict__ O)
{
    __shared__ float Qs[32][132];
    __shared__ float Ks[32][132];
    __shared__ float Vs[32][132];
    __shared__ float Ss[32][33];
    __shared__ float stat_s[3][32][2];
    const int tid = threadIdx.x;
    const int scene = blockIdx.x, h = blockIdx.y;

    if (tid < 96) {
        const int m = tid / 32, row = tid & 31;
        const float* p = ps + ((size_t)m * NN + scene * 32 + row) * 12;
        float s = 0.f, q = 0.f;
        #pragma unroll
        for (int c = 0; c < 6; ++c) { s += p[2 * c]; q += p[2 * c + 1]; }
        const float mu = s * (1.f / 768.f);
        const float var = q * (1.f / 768.f) - mu * mu;
        stat_s[m][row][0] = mu;
        stat_s[m][row][1] = rsqrtf(var + 1e-5f);
    }
    __syncthreads();

    // stage + normalize 3 x (32 rows x 128 cols)
    for (int m = 0; m < 3; ++m) {
        const float* Rm = R + (size_t)m * NN * HD;
        const float* g = (m == 0) ? gq : (m == 1) ? gk : gv;
        const float* b = (m == 0) ? bq : (m == 1) ? bk : bv;
        float* dst = (m == 0) ? &Qs[0][0] : (m == 1) ? &Ks[0][0] : &Vs[0][0];
        #pragma unroll
        for (int r = 0; r < 4; ++r) {
            const int idx = tid + r * 256;       // 0..1023 float4s
            const int row = idx >> 5, c4 = idx & 31;
            const float4 x = *(const float4*)(Rm + ((size_t)scene * 32 + row) * HD + h * 128 + c4 * 4);
            const float mu = stat_s[m][row][0], rs = stat_s[m][row][1];
            const float4 gg = *(const float4*)(g + h * 128 + c4 * 4);
            const float4 bb = *(const float4*)(b + h * 128 + c4 * 4);
            float4 y;
            y.x = (x.x - mu) * rs * gg.x + bb.x;
            y.y = (x.y - mu) * rs * gg.y + bb.y;
            y.z = (x.z - mu) * rs * gg.z + bb.z;
            y.w = (x.w - mu) * rs * gg.w + bb.w;
            if (m == 2) {
                y.x = fmaxf(y.x, 0.f); y.y = fmaxf(y.y, 0.f);
                y.z = fmaxf(y.z, 0.f); y.w = fmaxf(y.w, 0.f);
            }
            *(float4*)(dst + row * 132 + c4 * 4) = y;
        }
    }
    __syncthreads();

    // S = scale * Q K^T (2x2 blocking)
    {
        const int ti = tid >> 4, tj = tid & 15;
        float a00 = 0.f, a01 = 0.f, a10 = 0.f, a11 = 0.f;
        #pragma unroll 4
        for (int k4 = 0; k4 < 32; ++k4) {
            const float4 q0 = *(const float4*)&Qs[2 * ti][k4 * 4];
            const float4 q1 = *(const float4*)&Qs[2 * ti + 1][k4 * 4];
            const float4 k0 = *(const float4*)&Ks[2 * tj][k4 * 4];
            const float4 k1 = *(const float4*)&Ks[2 * tj + 1][k4 * 4];
            a00 += dot4(q0, k0); a01 += dot4(q0, k1);
            a10 += dot4(q1, k0); a11 += dot4(q1, k1);
        }
        const float scale = 0.08838834764831845f;  // 1/sqrt(128)
        Ss[2 * ti][2 * tj]         = a00 * scale;
        Ss[2 * ti][2 * tj + 1]     = a01 * scale;
        Ss[2 * ti + 1][2 * tj]     = a10 * scale;
        Ss[2 * ti + 1][2 * tj + 1] = a11 * scale;
    }
    __syncthreads();

    // exact row softmax (global max in reference cancels algebraically)
    {
        const int g = tid >> 5, l = tid & 31;
        #pragma unroll
        for (int ib = 0; ib < 4; ++ib) {
            const int i = g + ib * 8;
            const float sv = Ss[i][l];
            float mx = sv;
            #pragma unroll
            for (int mask = 16; mask >= 1; mask >>= 1)
                mx = fmaxf(mx, __shfl_xor(mx, mask));
            const float p = __expf(sv - mx);
            float sum = p;
            #pragma unroll
            for (int mask = 16; mask >= 1; mask >>= 1)
                sum += __shfl_xor(sum, mask);
            Ss[i][l] = p / sum;
        }
    }
    __syncthreads();

    // O = P V
    {
        const int i = tid >> 3, dg = tid & 7;
        float o[4][4] = {};
        for (int j = 0; j < 32; ++j) {
            const float p = Ss[i][j];
            #pragma unroll
            for (int r = 0; r < 4; ++r) {
                const float4 v4 = *(const float4*)&Vs[j][dg * 4 + 32 * r];
                o[r][0] += p * v4.x; o[r][1] += p * v4.y;
                o[r][2] += p * v4.z; o[r][3] += p * v4.w;
            }
        }
        const size_t base = ((size_t)scene * 32 + i) * HD + h * 128;
        #pragma unroll
        for (int r = 0; r < 4; ++r)
            *(float4*)(O + base + dg * 4 + 32 * r) =
                make_float4(o[r][0], o[r][1], o[r][2], o[r][3]);
    }
}

// ---------------------------------------------------------------------------
// K3a: P[kc] = O[:, kc*256:(kc+1)*256] @ Wo1[:, same]^T  (K-split partials)
// Block: 128 thr = 16 cg x 8 nodes, 8 cols/thread; grid (256, 3).
// ---------------------------------------------------------------------------
__global__ __launch_bounds__(128) void wo1_gemm_kernel(
    const float* __restrict__ O, const float* __restrict__ Wo1,
    float* __restrict__ P)    // [3][2048][128]
{
    __shared__ float Os[8][260];        // pitch 260: bank offset 4/row
    const int tid = threadIdx.x;
    const int cg = tid >> 3, n = tid & 7;
    const int ng = blockIdx.x, kc = blockIdx.y;
    const int n0 = ng * 8;

    {
        #pragma unroll
        for (int r = 0; r < 4; ++r) {
            const int idx = tid + r * 128;      // 0..511 float4s
            const int row = idx >> 6, c4 = idx & 63;
            *(float4*)&Os[row][c4 * 4] =
                *(const float4*)(O + ((size_t)n0 + row) * HD + kc * 256 + c4 * 4);
        }
    }
    __syncthreads();

    const int colbase = cg * 8;
    const float* wbase = Wo1 + (size_t)colbase * HD + kc * 256;
    float acc[8] = {0.f, 0.f, 0.f, 0.f, 0.f, 0.f, 0.f, 0.f};

    for (int k4 = 0; k4 < 64; k4 += 2) {
        const float4 a0 = *(const float4*)&Os[n][k4 * 4];
        const float4 a1 = *(const float4*)&Os[n][k4 * 4 + 4];
        #pragma unroll
        for (int jj = 0; jj < 8; ++jj) {
            const float4 w0 = *(const float4*)(wbase + (size_t)jj * HD + k4 * 4);
            const float4 w1 = *(const float4*)(wbase + (size_t)jj * HD + k4 * 4 + 4);
            acc[jj] += dot4(a0, w0) + dot4(a1, w1);
        }
    }

    float* pout = P + ((size_t)kc * NN + n0 + n) * 128 + colbase;
    *(float4*)pout       = make_float4(acc[0], acc[1], acc[2], acc[3]);
    *(float4*)(pout + 4) = make_float4(acc[4], acc[5], acc[6], acc[7]);
}

// ---------------------------------------------------------------------------
// K3b: t = relu(LN(P0+P1+P2)); u = t@Wo2^T + A@W1^T; z = relu(LN(u));
//      out = relu(z@W2^T + A).  Block: 128 thr, 8 nodes; grid 256.
// ---------------------------------------------------------------------------
__global__ __launch_bounds__(128) void epilogue_kernel(
    const float* __restrict__ P, const float* __restrict__ agents,
    const float* __restrict__ go, const float* __restrict__ bo,
    const float* __restrict__ Wo2, const float* __restrict__ W1,
    const float* __restrict__ gn, const float* __restrict__ bn,
    const float* __restrict__ W2, float* __restrict__ out)
{
    __shared__ float As[8][132];
    __shared__ float ts[8][132];
    __shared__ float zs[8][132];
    __shared__ float red[2][8][2];
    const int tid = threadIdx.x;
    const int cg = tid >> 3, n = tid & 7;
    const int n0 = blockIdx.x * 8;
    const int colbase = cg * 8;

    {
        const float4* src = (const float4*)(agents + (size_t)n0 * 128);
        #pragma unroll
        for (int r = 0; r < 2; ++r) {
            const int idx = tid + r * 128;
            const int row = idx >> 5, c4 = idx & 31;
            *(float4*)&As[row][c4 * 4] = src[idx];
        }
    }

    // t-acc = sum of 3 K-partials
    float acc[8];
    {
        const float* p0 = P + ((size_t)0 * NN + n0 + n) * 128 + colbase;
        const float* p1 = P + ((size_t)1 * NN + n0 + n) * 128 + colbase;
        const float* p2 = P + ((size_t)2 * NN + n0 + n) * 128 + colbase;
        #pragma unroll
        for (int r = 0; r < 2; ++r) {
            const float4 a = *(const float4*)(p0 + 4 * r);
            const float4 b = *(const float4*)(p1 + 4 * r);
            const float4 c = *(const float4*)(p2 + 4 * r);
            acc[4 * r]     = a.x + b.x + c.x;
            acc[4 * r + 1] = a.y + b.y + c.y;
            acc[4 * r + 2] = a.z + b.z + c.z;
            acc[4 * r + 3] = a.w + b.w + c.w;
        }
    }

    // LN(128) over 16 colgrps  -> ts = relu(LN*go+bo)
    {
        float s = 0.f, q = 0.f;
        #pragma unroll
        for (int jj = 0; jj < 8; ++jj) { s += acc[jj]; q += acc[jj] * acc[jj]; }
        #pragma unroll
        for (int mask = 8; mask <= 32; mask <<= 1) {
            s += __shfl_xor(s, mask); q += __shfl_xor(q, mask);
        }
        if ((tid & 63) < 8) { red[tid >> 6][tid & 7][0] = s; red[tid >> 6][tid & 7][1] = q; }
        __syncthreads();
        const float st = red[0][n][0] + red[1][n][0];
        const float qt = red[0][n][1] + red[1][n][1];
        const float mu = st * (1.f / 128.f);
        const float var = qt * (1.f / 128.f) - mu * mu;
        const float rs = rsqrtf(var + 1e-5f);
        float t[8];
        #pragma unroll
        for (int jj = 0; jj < 8; ++jj) {
            const int c = colbase + jj;
            t[jj] = fmaxf((acc[jj] - mu) * rs * go[c] + bo[c], 0.f);
        }
        *(float4*)&ts[n][colbase]     = make_float4(t[0], t[1], t[2], t[3]);
        *(float4*)&ts[n][colbase + 4] = make_float4(t[4], t[5], t[6], t[7]);
    }
    __syncthreads();

    // u = t@Wo2^T + A@W1^T
    float acc2[8] = {0.f, 0.f, 0.f, 0.f, 0.f, 0.f, 0.f, 0.f};
    for (int k4 = 0; k4 < 32; ++k4) {
        const float4 t4 = *(const float4*)&ts[n][k4 * 4];
        const float4 a4 = *(const float4*)&As[n][k4 * 4];
        #pragma unroll
        for (int jj = 0; jj < 8; ++jj) {
            const float4 w2 = *(const float4*)(Wo2 + (size_t)(colbase + jj) * 128 + k4 * 4);
            const float4 w1 = *(const float4*)(W1 + (size_t)(colbase + jj) * 128 + k4 * 4);
            acc2[jj] += dot4(t4, w2) + dot4(a4, w1);
        }
    }

    // LN(128) -> zs = relu(LN*gn+bn)
    {
        float s = 0.f, q = 0.f;
        #pragma unroll
        for (int jj = 0; jj < 8; ++jj) { s += acc2[jj]; q += acc2[jj] * acc2[jj]; }
        #pragma unroll
        for (int mask = 8; mask <= 32; mask <<= 1) {
            s += __shfl_xor(s, mask); q += __shfl_xor(q, mask);
        }
        __syncthreads();   // previous red[] reads complete
        if ((tid & 63) < 8) { red[tid >> 6][tid & 7][0] = s; red[tid >> 6][tid & 7][1] = q; }
        __syncthreads();
        const float st = red[0][n][0] + red[1][n][0];
        const float qt = red[0][n][1] + red[1][n][1];
        const float mu = st * (1.f / 128.f);
        const float var = qt * (1.f / 128.f) - mu * mu;
        const float rs = rsqrtf(var + 1e-5f);
        float z[8];
        #pragma unroll
        for (int jj = 0; jj < 8; ++jj) {
            const int c = colbase + jj;
            z[jj] = fmaxf((acc2[jj] - mu) * rs * gn[c] + bn[c], 0.f);
        }
        *(float4*)&zs[n][colbase]     = make_float4(z[0], z[1], z[2], z[3]);
        *(float4*)&zs[n][colbase + 4] = make_float4(z[4], z[5], z[6], z[7]);
    }
    __syncthreads();

    // out = relu(z@W2^T + A)
    float acc3[8] = {0.f, 0.f, 0.f, 0.f, 0.f, 0.f, 0.f, 0.f};
    for (int k4 = 0; k4 < 32; ++k4) {
        const float4 z4 = *(const float4*)&zs[n][k4 * 4];
        #pragma unroll
        for (int jj = 0; jj < 8; ++jj) {
            const float4 w = *(const float4*)(W2 + (size_t)(colbase + jj) * 128 + k4 * 4);
            acc3[jj] += dot4(z4, w);
        }
    }
    const float4 ar0 = *(const float4*)&As[n][colbase];
    const float4 ar1 = *(const float4*)&As[n][colbase + 4];
    float* op = out + ((size_t)n0 + n) * 128 + colbase;
    *(float4*)op = make_float4(fmaxf(acc3[0] + ar0.x, 0.f), fmaxf(acc3[1] + ar0.y, 0.f),
                               fmaxf(acc3[2] + ar0.z, 0.f), fmaxf(acc3[3] + ar0.w, 0.f));
    *(float4*)(op + 4) = make_float4(fmaxf(acc3[4] + ar1.x, 0.f), fmaxf(acc3[5] + ar1.y, 0.f),
                                     fmaxf(acc3[6] + ar1.z, 0.f), fmaxf(acc3[7] + ar1.w, 0.f));
}

// ---------------------------------------------------------------------------
extern "C" void kernel_launch(void* const* d_in, const int* in_sizes, int n_in,
                              void* d_out, int out_size, void* d_ws, size_t ws_size,
                              hipStream_t stream) {
    (void)in_sizes; (void)n_in; (void)out_size; (void)ws_size;
    const float* agents = (const float*)d_in[0];
    const float* Wq  = (const float*)d_in[3];
    const float* gq  = (const float*)d_in[4];
    const float* bq  = (const float*)d_in[5];
    const float* Wk  = (const float*)d_in[6];
    const float* gk  = (const float*)d_in[7];
    const float* bk  = (const float*)d_in[8];
    const float* Wv  = (const float*)d_in[9];
    const float* gv  = (const float*)d_in[10];
    const float* bv  = (const float*)d_in[11];
    const float* Wo1 = (const float*)d_in[12];
    const float* go  = (const float*)d_in[13];
    const float* bo  = (const float*)d_in[14];
    const float* Wo2 = (const float*)d_in[15];
    const float* W1  = (const float*)d_in[16];
    const float* gn  = (const float*)d_in[17];
    const float* bn  = (const float*)d_in[18];
    const float* W2  = (const float*)d_in[19];
    float* out = (float*)d_out;

    float* ws = (float*)d_ws;
    float* R  = ws;                                   // 3*2048*768
    float* ps = R + (size_t)3 * NN * HD;              // 3*2048*12
    float* O  = ps + (size_t)3 * NN * 12;             // 2048*768
    float* P  = R;                                    // alias: R dead after K2

    proj_gemm_kernel<<<dim3(NN / 8, 6, 3), 128, 0, stream>>>(agents, Wq, Wk, Wv, R, ps);
    attn_kernel<<<dim3(NB, HH), 256, 0, stream>>>(R, ps, gq, bq, gk, bk, gv, bv, O);
    wo1_gemm_kernel<<<dim3(NN / 8, 3), 128, 0, stream>>>(O, Wo1, P);
    epilogue_kernel<<<NN / 8, 128, 0, stream>>>(P, agents, go, bo, Wo2, W1, gn, bn, W2, out);
}